// Round 13
// baseline (289.393 us; speedup 1.0000x reference)
//
#include <hip/hip_runtime.h>

// Problem constants (B=16, T=2048, D=512, A=128)
#define NB 16
#define NT 2048
#define ND 512
#define NA 128
#define EPSV 1e-6f
#define SCALE 0.08838834764831845f  // 128^-0.5
#define NCH 16       // s-chunks (128 rows each)
#define SCH 128      // s-chunk length (rows resident in LDS)
#define NTSL 4       // t-slices (512 t-rows each)

typedef __bf16 bf16;
typedef __bf16 bf16x4 __attribute__((ext_vector_type(4)));
typedef __bf16 bf16x8 __attribute__((ext_vector_type(8)));
typedef float f32x4 __attribute__((ext_vector_type(4)));

// ---------------------------------------------------------------------------
// Kernel 0: build W^T bf16 [256][512]  (rows 0..127 = Wq cols, 128..255 = Wk)
// ---------------------------------------------------------------------------
__global__ void prep_wt(const float* __restrict__ Wq, const float* __restrict__ Wk,
                        bf16* __restrict__ WT) {
    int n = blockIdx.x;
    const float* W = (n < NA) ? Wq : Wk;
    int col = n & (NA - 1);
    for (int k = threadIdx.x; k < ND; k += blockDim.x)
        WT[(size_t)n * ND + k] = (bf16)W[(size_t)k * NA + col];
}

// ---------------------------------------------------------------------------
// Kernel 1: fused norm + V + QK projection GEMM. 16 rows/block, grid 2048.
// Writes SPLIT Q / K arrays (each [B*T][128] bf16) for dense attn reads.
// ---------------------------------------------------------------------------
__launch_bounds__(256)
__global__ void norm_proj(const float* __restrict__ x, const float* __restrict__ Wv,
                          const float* __restrict__ bvp, const bf16* __restrict__ WT,
                          const float* __restrict__ bq, const float* __restrict__ bk,
                          bf16* __restrict__ Qm, bf16* __restrict__ Km,
                          float* __restrict__ Vout) {
    __shared__ bf16 xn[16 * ND];  // 16 KB, XOR-swizzled rows
    const int tid = threadIdx.x;
    const int lane = tid & 63, wv = tid >> 6;
    const int row0 = blockIdx.x * 16;

    float wvv[8];
    float sumw = 0.f;
#pragma unroll
    for (int i = 0; i < 4; ++i) { wvv[i]     = Wv[lane * 4 + i];       sumw += wvv[i]; }
#pragma unroll
    for (int i = 0; i < 4; ++i) { wvv[4 + i] = Wv[256 + lane * 4 + i]; sumw += wvv[4 + i]; }
#pragma unroll
    for (int m = 1; m < 64; m <<= 1) sumw += __shfl_xor(sumw, m);
    const float bvs = bvp[0];

#pragma unroll
    for (int r = 0; r < 4; ++r) {
        const int lrow = wv * 4 + r;
        const int grow = row0 + lrow;
        const float* xr = x + (size_t)grow * ND;
        f32x4 a = *(const f32x4*)(xr + lane * 4);
        f32x4 b = *(const f32x4*)(xr + 256 + lane * 4);
        float s = 0.f, sq = 0.f, dw = 0.f;
#pragma unroll
        for (int i = 0; i < 4; ++i) { s += a[i]; sq += a[i] * a[i]; dw += a[i] * wvv[i]; }
#pragma unroll
        for (int i = 0; i < 4; ++i) { s += b[i]; sq += b[i] * b[i]; dw += b[i] * wvv[4 + i]; }
#pragma unroll
        for (int m = 1; m < 64; m <<= 1) {
            s  += __shfl_xor(s, m);
            sq += __shfl_xor(sq, m);
            dw += __shfl_xor(dw, m);
        }
        const float mu  = s * (1.f / 512.f);
        float var = (sq - 512.f * mu * mu) * (1.f / 511.f);
        var = fmaxf(var, 0.f);
        const float inv = 1.f / (sqrtf(var) + EPSV);
        if (lane == 0) Vout[grow] = (dw - mu * sumw) * inv + bvs;

        const int sw = (lrow & 7) << 4;
        bf16x4 v0, v1;
#pragma unroll
        for (int i = 0; i < 4; ++i) v0[i] = (bf16)((a[i] - mu) * inv);
#pragma unroll
        for (int i = 0; i < 4; ++i) v1[i] = (bf16)((b[i] - mu) * inv);
        *(bf16x4*)((char*)xn + lrow * 1024 + ((lane * 8) ^ sw))       = v0;
        *(bf16x4*)((char*)xn + lrow * 1024 + ((512 + lane * 8) ^ sw)) = v1;
    }
    __syncthreads();

    const int c = lane & 15, g = lane >> 4;
    const int asw = (c & 7) << 4;
    f32x4 acc[4];
#pragma unroll
    for (int i = 0; i < 4; ++i) acc[i] = f32x4{0.f, 0.f, 0.f, 0.f};

    for (int ks = 0; ks < 16; ++ks) {
        const bf16x8 af = *(const bf16x8*)((const char*)xn + c * 1024 +
                                           ((ks * 64 + g * 16) ^ asw));
#pragma unroll
        for (int i = 0; i < 4; ++i) {
            const int n = wv * 64 + i * 16 + c;
            const bf16x8 bfr = *(const bf16x8*)(WT + (size_t)n * ND + ks * 32 + g * 8);
            acc[i] = __builtin_amdgcn_mfma_f32_16x16x32_bf16(af, bfr, acc[i], 0, 0, 0);
        }
    }
#pragma unroll
    for (int i = 0; i < 4; ++i) {
        const int n = wv * 64 + i * 16 + c;
        const float bias = (n < NA) ? bq[n] : bk[n - NA];
        bf16* dst = (n < NA) ? (Qm + n) : (Km + (n - NA));
#pragma unroll
        for (int j = 0; j < 4; ++j)
            dst[(size_t)(row0 + g * 4 + j) * NA] = (bf16)(acc[i][j] + bias);
    }
}

// ---------------------------------------------------------------------------
// Kernel 2: pass1 — chunk-resident: stage 128 K-rows (32 KB) once, then loop
// 512 t-rows with ZERO further barriers/staging. Partials into out_att scratch.
// Grid (tsl=4, sc=16, b=16) = 1024 blocks, 4 blocks/CU.
// ---------------------------------------------------------------------------
__launch_bounds__(256, 4)
__global__ void attn_pass1(const bf16* __restrict__ Qm, const bf16* __restrict__ Km,
                           const float* __restrict__ Vg,
                           float* __restrict__ pl, float* __restrict__ pw) {
    __shared__ bf16 Kt[SCH * NA];  // 32 KB, XOR-swizzled
    const int tid = threadIdx.x;
    const int lane = tid & 63, wv = tid >> 6;
    const int tsl = blockIdx.x, sc = blockIdx.y, b = blockIdx.z;
    const int c = lane & 15, g = lane >> 4;

    // one-time chunk staging (contiguous dense reads)
    {
        const int srow = tid >> 4, scc = tid & 15;
        const bf16* kbase = Km + (size_t)(b * NT + sc * SCH + srow) * NA + scc * 8;
        char* kdst = (char*)Kt + srow * 256 + ((scc * 16) ^ ((srow & 7) << 4));
#pragma unroll
        for (int i = 0; i < 8; ++i) {
            const bf16x8 v = *(const bf16x8*)(kbase + (size_t)(i * 16) * NA);
            *(bf16x8*)(kdst + i * 16 * 256) = v;
        }
    }
    __syncthreads();

    const float* vbase = Vg + b * NT + sc * SCH;

    for (int ti = 0; ti < 8; ++ti) {
        const int trow = tsl * 512 + ti * 64 + wv * 16 + c;
        const bf16* qrow = Qm + (size_t)(b * NT + trow) * NA;
        bf16x8 qf[4];
#pragma unroll
        for (int ks = 0; ks < 4; ++ks) qf[ks] = *(const bf16x8*)(qrow + ks * 32 + g * 8);

        float l_loc = 0.f, w_loc = 0.f;
#pragma unroll
        for (int ns = 0; ns < 8; ++ns) {
            f32x4 acc = f32x4{0.f, 0.f, 0.f, 0.f};
            const int rr = ns * 16 + c;
            const int rsw = (rr & 7) << 4;
#pragma unroll
            for (int ks = 0; ks < 4; ++ks) {
                const bf16x8 afr = *(const bf16x8*)((const char*)Kt + rr * 256 +
                                                    ((ks * 64 + g * 16) ^ rsw));
                acc = __builtin_amdgcn_mfma_f32_16x16x32_bf16(afr, qf[ks], acc, 0, 0, 0);
            }
            const f32x4 vv = *(const f32x4*)(vbase + ns * 16 + g * 4);
#pragma unroll
            for (int jj = 0; jj < 4; ++jj) {
                const float p = __expf(acc[jj] * SCALE);
                l_loc += p;
                w_loc += p * vv[jj];
            }
        }
#pragma unroll
        for (int mask = 16; mask <= 32; mask <<= 1) {
            l_loc += __shfl_xor(l_loc, mask);
            w_loc += __shfl_xor(w_loc, mask);
        }
        if (g == 0) {
            const int idx = sc * (NB * NT) + b * NT + trow;
            pl[idx] = l_loc;
            pw[idx] = w_loc;
        }
    }
}

// ---------------------------------------------------------------------------
// Kernel 3: merge the 16 chunk-partials -> 1/l, out_w
// ---------------------------------------------------------------------------
__global__ void attn_reduce(const float* __restrict__ pl, const float* __restrict__ pw,
                            float* __restrict__ linv, float* __restrict__ out_w) {
    const int r = blockIdx.x * 256 + threadIdx.x;  // 0 .. NB*NT-1
    float L = 0.f, W = 0.f;
#pragma unroll
    for (int ch = 0; ch < NCH; ++ch) {
        L += pl[ch * (NB * NT) + r];
        W += pw[ch * (NB * NT) + r];
    }
    linv[r] = 1.f / L;
    out_w[r] = W / L;
}

// ---------------------------------------------------------------------------
// Kernel 4: pass2 — same chunk-resident structure; recompute + store.
// ---------------------------------------------------------------------------
__launch_bounds__(256, 4)
__global__ void attn_pass2(const bf16* __restrict__ Qm, const bf16* __restrict__ Km,
                           const float* __restrict__ linv, float* __restrict__ out_att) {
    __shared__ bf16 Kt[SCH * NA];  // 32 KB
    const int tid = threadIdx.x;
    const int lane = tid & 63, wv = tid >> 6;
    const int tsl = blockIdx.x, sc = blockIdx.y, b = blockIdx.z;
    const int c = lane & 15, g = lane >> 4;

    {
        const int srow = tid >> 4, scc = tid & 15;
        const bf16* kbase = Km + (size_t)(b * NT + sc * SCH + srow) * NA + scc * 8;
        char* kdst = (char*)Kt + srow * 256 + ((scc * 16) ^ ((srow & 7) << 4));
#pragma unroll
        for (int i = 0; i < 8; ++i) {
            const bf16x8 v = *(const bf16x8*)(kbase + (size_t)(i * 16) * NA);
            *(bf16x8*)(kdst + i * 16 * 256) = v;
        }
    }
    __syncthreads();

    for (int ti = 0; ti < 8; ++ti) {
        const int trow = tsl * 512 + ti * 64 + wv * 16 + c;
        const bf16* qrow = Qm + (size_t)(b * NT + trow) * NA;
        bf16x8 qf[4];
#pragma unroll
        for (int ks = 0; ks < 4; ++ks) qf[ks] = *(const bf16x8*)(qrow + ks * 32 + g * 8);
        const float lrow = linv[b * NT + trow];
        float* orow = out_att + (size_t)(b * NT + trow) * NT + sc * SCH;

#pragma unroll
        for (int ns = 0; ns < 8; ++ns) {
            f32x4 acc = f32x4{0.f, 0.f, 0.f, 0.f};
            const int rr = ns * 16 + c;
            const int rsw = (rr & 7) << 4;
#pragma unroll
            for (int ks = 0; ks < 4; ++ks) {
                const bf16x8 afr = *(const bf16x8*)((const char*)Kt + rr * 256 +
                                                    ((ks * 64 + g * 16) ^ rsw));
                acc = __builtin_amdgcn_mfma_f32_16x16x32_bf16(afr, qf[ks], acc, 0, 0, 0);
            }
            f32x4 w;
#pragma unroll
            for (int jj = 0; jj < 4; ++jj)
                w[jj] = __expf(acc[jj] * SCALE) * lrow;
            *(f32x4*)(orow + ns * 16 + g * 4) = w;
        }
    }
}

// ---------------------------------------------------------------------------
extern "C" void kernel_launch(void* const* d_in, const int* in_sizes, int n_in,
                              void* d_out, int out_size, void* d_ws, size_t ws_size,
                              hipStream_t stream) {
    const float* x  = (const float*)d_in[0];
    const float* Wq = (const float*)d_in[1];
    const float* bq = (const float*)d_in[2];
    const float* Wk = (const float*)d_in[3];
    const float* bk = (const float*)d_in[4];
    const float* Wv = (const float*)d_in[5];
    const float* bv = (const float*)d_in[6];

    float* out_w   = (float*)d_out;            // [B,T,1] = 32768
    float* out_att = (float*)d_out + NB * NT;  // [B,T,T]

    char* ws = (char*)d_ws;
    bf16*  WT   = (bf16*)ws;                         // 262144 B
    float* V    = (float*)(ws + 262144);             // 131072 B
    bf16*  Qm   = (bf16*)(ws + 393216);              // 8 MB
    bf16*  Km   = (bf16*)(ws + 393216 + 8388608);    // 8 MB
    float* linv = (float*)(ws + 17170432);           // 128 KB

    // partials live in the head of out_att (dead until pass2 overwrites;
    // stream order guarantees reduce consumes them first): 2 x 2 MB
    float* pl = out_att;
    float* pw = out_att + NCH * (NB * NT);

    prep_wt<<<dim3(256), dim3(256), 0, stream>>>(Wq, Wk, WT);
    norm_proj<<<dim3((NB * NT) / 16), dim3(256), 0, stream>>>(x, Wv, bv, WT, bq, bk, Qm, Km, V);
    attn_pass1<<<dim3(NTSL, NCH, NB), dim3(256), 0, stream>>>(Qm, Km, V, pl, pw);
    attn_reduce<<<dim3((NB * NT) / 256), dim3(256), 0, stream>>>(pl, pw, linv, out_w);
    attn_pass2<<<dim3(NTSL, NCH, NB), dim3(256), 0, stream>>>(Qm, Km, linv, out_att);
}

// Round 15
// 173.903 us; speedup vs baseline: 1.6641x; 1.6641x over previous
//
#include <hip/hip_runtime.h>

// Problem constants (B=16, T=2048, D=512, A=128)
#define NB 16
#define NT 2048
#define ND 512
#define NA 128
#define EPSV 1e-6f
#define SCALE 0.08838834764831845f  // 128^-0.5
#define NCH 4        // s-chunks in attention
#define SCH 512      // s-chunk length

typedef __bf16 bf16;
typedef __bf16 bf16x4 __attribute__((ext_vector_type(4)));
typedef __bf16 bf16x8 __attribute__((ext_vector_type(8)));
typedef float f32x4 __attribute__((ext_vector_type(4)));

// ---------------------------------------------------------------------------
// Kernel 0: build W^T bf16 [256][512]  (rows 0..127 = Wq cols, 128..255 = Wk)
// ---------------------------------------------------------------------------
__global__ void prep_wt(const float* __restrict__ Wq, const float* __restrict__ Wk,
                        bf16* __restrict__ WT) {
    int n = blockIdx.x;
    const float* W = (n < NA) ? Wq : Wk;
    int col = n & (NA - 1);
    for (int k = threadIdx.x; k < ND; k += blockDim.x)
        WT[(size_t)n * ND + k] = (bf16)W[(size_t)k * NA + col];
}

// ---------------------------------------------------------------------------
// Kernel 1: fused norm + V + QK projection GEMM. 16 rows/block, grid 2048.
// ---------------------------------------------------------------------------
__launch_bounds__(256)
__global__ void norm_proj(const float* __restrict__ x, const float* __restrict__ Wv,
                          const float* __restrict__ bvp, const bf16* __restrict__ WT,
                          const float* __restrict__ bq, const float* __restrict__ bk,
                          bf16* __restrict__ QK, float* __restrict__ Vout) {
    __shared__ bf16 xn[16 * ND];  // 16 KB, XOR-swizzled rows
    const int tid = threadIdx.x;
    const int lane = tid & 63, wv = tid >> 6;
    const int row0 = blockIdx.x * 16;

    float wvv[8];
    float sumw = 0.f;
#pragma unroll
    for (int i = 0; i < 4; ++i) { wvv[i]     = Wv[lane * 4 + i];       sumw += wvv[i]; }
#pragma unroll
    for (int i = 0; i < 4; ++i) { wvv[4 + i] = Wv[256 + lane * 4 + i]; sumw += wvv[4 + i]; }
#pragma unroll
    for (int m = 1; m < 64; m <<= 1) sumw += __shfl_xor(sumw, m);
    const float bvs = bvp[0];

#pragma unroll
    for (int r = 0; r < 4; ++r) {
        const int lrow = wv * 4 + r;
        const int grow = row0 + lrow;
        const float* xr = x + (size_t)grow * ND;
        f32x4 a = *(const f32x4*)(xr + lane * 4);
        f32x4 b = *(const f32x4*)(xr + 256 + lane * 4);
        float s = 0.f, sq = 0.f, dw = 0.f;
#pragma unroll
        for (int i = 0; i < 4; ++i) { s += a[i]; sq += a[i] * a[i]; dw += a[i] * wvv[i]; }
#pragma unroll
        for (int i = 0; i < 4; ++i) { s += b[i]; sq += b[i] * b[i]; dw += b[i] * wvv[4 + i]; }
#pragma unroll
        for (int m = 1; m < 64; m <<= 1) {
            s  += __shfl_xor(s, m);
            sq += __shfl_xor(sq, m);
            dw += __shfl_xor(dw, m);
        }
        const float mu  = s * (1.f / 512.f);
        float var = (sq - 512.f * mu * mu) * (1.f / 511.f);
        var = fmaxf(var, 0.f);
        const float inv = 1.f / (sqrtf(var) + EPSV);
        if (lane == 0) Vout[grow] = (dw - mu * sumw) * inv + bvs;

        const int sw = (lrow & 7) << 4;
        bf16x4 v0, v1;
#pragma unroll
        for (int i = 0; i < 4; ++i) v0[i] = (bf16)((a[i] - mu) * inv);
#pragma unroll
        for (int i = 0; i < 4; ++i) v1[i] = (bf16)((b[i] - mu) * inv);
        *(bf16x4*)((char*)xn + lrow * 1024 + ((lane * 8) ^ sw))       = v0;
        *(bf16x4*)((char*)xn + lrow * 1024 + ((512 + lane * 8) ^ sw)) = v1;
    }
    __syncthreads();

    const int c = lane & 15, g = lane >> 4;
    const int asw = (c & 7) << 4;
    f32x4 acc[4];
#pragma unroll
    for (int i = 0; i < 4; ++i) acc[i] = f32x4{0.f, 0.f, 0.f, 0.f};

    for (int ks = 0; ks < 16; ++ks) {
        const bf16x8 af = *(const bf16x8*)((const char*)xn + c * 1024 +
                                           ((ks * 64 + g * 16) ^ asw));
#pragma unroll
        for (int i = 0; i < 4; ++i) {
            const int n = wv * 64 + i * 16 + c;
            const bf16x8 bfr = *(const bf16x8*)(WT + (size_t)n * ND + ks * 32 + g * 8);
            acc[i] = __builtin_amdgcn_mfma_f32_16x16x32_bf16(af, bfr, acc[i], 0, 0, 0);
        }
    }
#pragma unroll
    for (int i = 0; i < 4; ++i) {
        const int n = wv * 64 + i * 16 + c;
        const float bias = (n < NA) ? bq[n] : bk[n - NA];
#pragma unroll
        for (int j = 0; j < 4; ++j)
            QK[(size_t)(row0 + g * 4 + j) * 256 + n] = (bf16)(acc[i][j] + bias);
    }
}

// ---------------------------------------------------------------------------
// Kernel 2: pass1 — per-chunk sums l = sum(exp s), w = sum(exp s * V).
// R11 structure exactly (issue-early/write-late).
// ---------------------------------------------------------------------------
__launch_bounds__(256)
__global__ void attn_pass1(const bf16* __restrict__ QK, const float* __restrict__ Vg,
                           float* __restrict__ pl, float* __restrict__ pw) {
    __shared__ bf16 Kt[64 * NA];  // 16 KB, XOR-swizzled
    const int tid = threadIdx.x;
    const int lane = tid & 63, wv = tid >> 6;
    const int b = blockIdx.z, t0 = blockIdx.x * 64, sc = blockIdx.y;
    const int c = lane & 15, g = lane >> 4;
    const int trow = t0 + wv * 16 + c;

    bf16x8 qf[4];
    const bf16* qrow = QK + (size_t)(b * NT + trow) * 256;
#pragma unroll
    for (int ks = 0; ks < 4; ++ks) qf[ks] = *(const bf16x8*)(qrow + ks * 32 + g * 8);

    const int srow = tid >> 4, scc = tid & 15;
    const bf16* kbase = QK + (size_t)(b * NT + sc * SCH + srow) * 256 + NA + scc * 8;
    bf16* kdst = (bf16*)((char*)Kt + srow * 256 + ((scc * 16) ^ ((srow & 7) << 4)));
    bf16x8 sreg[4];

    // prologue: stage tile 0
#pragma unroll
    for (int i = 0; i < 4; ++i)
        sreg[i] = *(const bf16x8*)(kbase + (size_t)(i * 16) * 256);
#pragma unroll
    for (int i = 0; i < 4; ++i)
        *(bf16x8*)((char*)kdst + i * 16 * 256) = sreg[i];
    __syncthreads();

    const float* vbase = Vg + b * NT + sc * SCH;
    float l_loc = 0.f, w_loc = 0.f;

    for (int tt = 0; tt < SCH / 64; ++tt) {
        if (tt + 1 < SCH / 64) {  // issue next-tile loads BEFORE compute
#pragma unroll
            for (int i = 0; i < 4; ++i)
                sreg[i] = *(const bf16x8*)(kbase + (size_t)((tt + 1) * 64 + i * 16) * 256);
        }

#pragma unroll
        for (int ns = 0; ns < 4; ++ns) {
            f32x4 acc = f32x4{0.f, 0.f, 0.f, 0.f};
            const int rr = ns * 16 + c;
            const int rsw = (rr & 7) << 4;
#pragma unroll
            for (int ks = 0; ks < 4; ++ks) {
                const bf16x8 afr = *(const bf16x8*)((const char*)Kt + rr * 256 +
                                                    ((ks * 64 + g * 16) ^ rsw));
                acc = __builtin_amdgcn_mfma_f32_16x16x32_bf16(afr, qf[ks], acc, 0, 0, 0);
            }
            const f32x4 vv = *(const f32x4*)(vbase + tt * 64 + ns * 16 + g * 4);
#pragma unroll
            for (int jj = 0; jj < 4; ++jj) {
                const float p = __expf(acc[jj] * SCALE);
                l_loc += p;
                w_loc += p * vv[jj];
            }
        }

        if (tt + 1 < SCH / 64) {
            __syncthreads();  // waves done reading Kt; drain covered by compute
#pragma unroll
            for (int i = 0; i < 4; ++i)
                *(bf16x8*)((char*)kdst + i * 16 * 256) = sreg[i];
            __syncthreads();  // Kt visible
        }
    }

#pragma unroll
    for (int mask = 16; mask <= 32; mask <<= 1) {
        l_loc += __shfl_xor(l_loc, mask);
        w_loc += __shfl_xor(w_loc, mask);
    }
    if (g == 0) {
        const int idx = sc * (NB * NT) + b * NT + trow;
        pl[idx] = l_loc;
        pw[idx] = w_loc;
    }
}

// ---------------------------------------------------------------------------
// Kernel 3: pass2 — folds the 4 chunk-partials per-thread (L2-hot), writes
// out_w (sc==0), recomputes scores, writes normalized w_att.
// R11 schedule otherwise unchanged.
// ---------------------------------------------------------------------------
__launch_bounds__(256)
__global__ void attn_pass2(const bf16* __restrict__ QK, const float* __restrict__ pl,
                           const float* __restrict__ pw, float* __restrict__ out_w,
                           float* __restrict__ out_att) {
    __shared__ bf16 Kt[64 * NA];
    const int tid = threadIdx.x;
    const int lane = tid & 63, wv = tid >> 6;
    const int b = blockIdx.z, t0 = blockIdx.x * 64, sc = blockIdx.y;
    const int c = lane & 15, g = lane >> 4;
    const int trow = t0 + wv * 16 + c;

    bf16x8 qf[4];
    const bf16* qrow = QK + (size_t)(b * NT + trow) * 256;
#pragma unroll
    for (int ks = 0; ks < 4; ++ks) qf[ks] = *(const bf16x8*)(qrow + ks * 32 + g * 8);

    // fold partials (8 coalesced L2-hot loads)
    float L = 0.f, W = 0.f;
#pragma unroll
    for (int ch = 0; ch < NCH; ++ch) {
        L += pl[ch * (NB * NT) + b * NT + trow];
        W += pw[ch * (NB * NT) + b * NT + trow];
    }
    const float lrow = 1.f / L;
    if (sc == 0 && g == 0) out_w[b * NT + trow] = W * lrow;

    float* orow = out_att + (size_t)(b * NT + trow) * NT;

    const int srow = tid >> 4, scc = tid & 15;
    const bf16* kbase = QK + (size_t)(b * NT + sc * SCH + srow) * 256 + NA + scc * 8;
    bf16* kdst = (bf16*)((char*)Kt + srow * 256 + ((scc * 16) ^ ((srow & 7) << 4)));
    bf16x8 sreg[4];

#pragma unroll
    for (int i = 0; i < 4; ++i)
        sreg[i] = *(const bf16x8*)(kbase + (size_t)(i * 16) * 256);
#pragma unroll
    for (int i = 0; i < 4; ++i)
        *(bf16x8*)((char*)kdst + i * 16 * 256) = sreg[i];
    __syncthreads();

    for (int tt = 0; tt < SCH / 64; ++tt) {
        if (tt + 1 < SCH / 64) {  // issue next-tile loads BEFORE compute
#pragma unroll
            for (int i = 0; i < 4; ++i)
                sreg[i] = *(const bf16x8*)(kbase + (size_t)((tt + 1) * 64 + i * 16) * 256);
        }

        const int s0 = sc * SCH + tt * 64;
#pragma unroll
        for (int ns = 0; ns < 4; ++ns) {
            f32x4 acc = f32x4{0.f, 0.f, 0.f, 0.f};
            const int rr = ns * 16 + c;
            const int rsw = (rr & 7) << 4;
#pragma unroll
            for (int ks = 0; ks < 4; ++ks) {
                const bf16x8 afr = *(const bf16x8*)((const char*)Kt + rr * 256 +
                                                    ((ks * 64 + g * 16) ^ rsw));
                acc = __builtin_amdgcn_mfma_f32_16x16x32_bf16(afr, qf[ks], acc, 0, 0, 0);
            }
            f32x4 w;
#pragma unroll
            for (int jj = 0; jj < 4; ++jj)
                w[jj] = __expf(acc[jj] * SCALE) * lrow;
            *(f32x4*)(orow + s0 + ns * 16 + g * 4) = w;
        }

        if (tt + 1 < SCH / 64) {
            __syncthreads();
#pragma unroll
            for (int i = 0; i < 4; ++i)
                *(bf16x8*)((char*)kdst + i * 16 * 256) = sreg[i];
            __syncthreads();
        }
    }
}

// ---------------------------------------------------------------------------
extern "C" void kernel_launch(void* const* d_in, const int* in_sizes, int n_in,
                              void* d_out, int out_size, void* d_ws, size_t ws_size,
                              hipStream_t stream) {
    const float* x  = (const float*)d_in[0];
    const float* Wq = (const float*)d_in[1];
    const float* bq = (const float*)d_in[2];
    const float* Wk = (const float*)d_in[3];
    const float* bk = (const float*)d_in[4];
    const float* Wv = (const float*)d_in[5];
    const float* bv = (const float*)d_in[6];

    float* out_w   = (float*)d_out;            // [B,T,1] = 32768
    float* out_att = (float*)d_out + NB * NT;  // [B,T,T]

    char* ws = (char*)d_ws;
    bf16*  WT = (bf16*)ws;                       // 262144 B
    float* V  = (float*)(ws + 262144);           // 131072 B
    bf16*  QK = (bf16*)(ws + 393216);            // 16 MB
    float* pl = (float*)(ws + 17170432);         // 512 KB
    float* pw = (float*)(ws + 17694720);         // 512 KB

    prep_wt<<<dim3(256), dim3(256), 0, stream>>>(Wq, Wk, WT);
    norm_proj<<<dim3((NB * NT) / 16), dim3(256), 0, stream>>>(x, Wv, bv, WT, bq, bk, QK, V);
    attn_pass1<<<dim3(NT / 64, NCH, NB), dim3(256), 0, stream>>>(QK, V, pl, pw);
    attn_pass2<<<dim3(NT / 64, NCH, NB), dim3(256), 0, stream>>>(QK, pl, pw, out_w, out_att);
}